// Round 7
// baseline (206.402 us; speedup 1.0000x reference)
//
#include <hip/hip_runtime.h>
#include <math.h>

#define IN_NODES  4096
#define OUT_NODES 1024
#define ROW_ELEMS 16384          // floats per in-node row
#define ROW_C4    4096           // float4 chunks per row
#define ROW_U4    2048           // uint4 (8xbf16) chunks per row
#define G_UNI     256            // blocks for uniform pass (1024 thr)
#define G_SOFT    512            // blocks for softmax passes (512 thr)

typedef unsigned short u16;
typedef unsigned int   u32;

__device__ __forceinline__ float dot4(const float4 a, const float4 b) {
    return a.x*b.x + a.y*b.y + a.z*b.z + a.w*b.w;
}
__device__ __forceinline__ void fma4(float4& a, const float c, const float4 u) {
    a.x += c*u.x; a.y += c*u.y; a.z += c*u.z; a.w += c*u.w;
}
__device__ __forceinline__ void add4(float4& a, const float4 u) {
    a.x += u.x; a.y += u.y; a.z += u.z; a.w += u.w;
}
__device__ __forceinline__ u16 f2b(float x) {            // RNE f32->bf16
    u32 b = __float_as_uint(x);
    return (u16)((b + 0x7FFFu + ((b >> 16) & 1u)) >> 16);
}
__device__ __forceinline__ ushort4 f2b4(float4 v) {
    ushort4 r; r.x = f2b(v.x); r.y = f2b(v.y); r.z = f2b(v.z); r.w = f2b(v.w);
    return r;
}
// uint4 = 8 bf16 (memory order) -> two float4
__device__ __forceinline__ void unpack8(const uint4 w, float4& lo, float4& hi) {
    lo.x = __uint_as_float(w.x << 16);
    lo.y = __uint_as_float(w.x & 0xFFFF0000u);
    lo.z = __uint_as_float(w.y << 16);
    lo.w = __uint_as_float(w.y & 0xFFFF0000u);
    hi.x = __uint_as_float(w.z << 16);
    hi.y = __uint_as_float(w.z & 0xFFFF0000u);
    hi.z = __uint_as_float(w.w << 16);
    hi.w = __uint_as_float(w.w & 0xFFFF0000u);
}

// ---------------------------------------------------------------------------
// K0: uniform pass (c = 1/1024) + bf16 copy. 256 blocks x 1024 thr, no
// barriers, ~45 VGPR. Thread owns float4 chunks c0 + j*64, all loads/stores
// contiguous per instruction. (Unchanged from R6 — memory-bound already.)
// ---------------------------------------------------------------------------
__global__ __launch_bounds__(1024) void k_uniform(const float* __restrict__ uh,
                                                  u16* __restrict__ uh2,
                                                  float* __restrict__ part) {
    const int t    = threadIdx.x;
    const int wave = t >> 6;
    const int lane = t & 63;
    const int c0   = (wave << 8) + lane;
    const int PB   = IN_NODES / G_UNI;         // 16

    float4 acc[4];
    #pragma unroll
    for (int j = 0; j < 4; ++j) acc[j] = make_float4(0.f, 0.f, 0.f, 0.f);

    const float4* p = reinterpret_cast<const float4*>(uh)
                    + (size_t)blockIdx.x * PB * ROW_C4 + c0;
    ushort4* q = reinterpret_cast<ushort4*>(uh2)
               + (size_t)blockIdx.x * PB * ROW_C4 + c0;

    for (int g = 0; g < PB; ++g) {
        float4 u[4];
        #pragma unroll
        for (int j = 0; j < 4; ++j) u[j] = p[j * 64];
        #pragma unroll
        for (int j = 0; j < 4; ++j) { add4(acc[j], u[j]); q[j * 64] = f2b4(u[j]); }
        p += ROW_C4; q += ROW_C4;
    }

    const float c = 1.0f / OUT_NODES;
    float4* sp = reinterpret_cast<float4*>(part) + (size_t)blockIdx.x * ROW_C4 + c0;
    #pragma unroll
    for (int j = 0; j < 4; ++j) {
        acc[j].x *= c; acc[j].y *= c; acc[j].z *= c; acc[j].w *= c;
        sp[j * 64] = acc[j];
    }
}

// ---------------------------------------------------------------------------
// K_soft: softmax pass over the bf16 copy. 512 blocks x 512 thr, ~115 VGPR
// under __launch_bounds__(512,4) -> 4 waves/SIMD -> 2 blocks/CU: while one
// block sits in its denom-reduction barriers, the other block's loads/FMAs
// keep the CU busy. Thread owns uint4 units u_j = j*512 + t (j=0..3); unit u
// is half of out-node o = u>>1 (even/odd lane pairs share o -> shfl_xor(1)
// completes d[o]). One row per barrier pair; next row prefetched before the
// reduction so its loads are in flight across the barriers. Unpack recomputed
// in the FMA phase (reg-lean). No max-subtraction: |d| < ~15, f32 exp safe.
// ---------------------------------------------------------------------------
__global__ __launch_bounds__(512, 4) void k_soft(const u16* __restrict__ uh2,
                                                 const float* __restrict__ V,
                                                 float* __restrict__ part) {
    const int t    = threadIdx.x;
    const int wave = t >> 6;
    const int lane = t & 63;
    const int PB   = IN_NODES / G_SOFT;        // 8

    __shared__ float red8[8];
    __shared__ float redS;

    float4 v[8];
    {
        const float4* vp = reinterpret_cast<const float4*>(V);
        #pragma unroll
        for (int j = 0; j < 4; ++j) {
            const int u = j * 512 + t;
            v[2*j]   = vp[2*u];
            v[2*j+1] = vp[2*u + 1];
        }
    }

    float4 acc[8];
    #pragma unroll
    for (int j = 0; j < 8; ++j) acc[j] = make_float4(0.f, 0.f, 0.f, 0.f);

    const uint4* p = reinterpret_cast<const uint4*>(uh2)
                   + (size_t)blockIdx.x * PB * ROW_U4;

    uint4 cur[4];
    #pragma unroll
    for (int j = 0; j < 4; ++j) cur[j] = p[j * 512 + t];

    for (int g = 0; g < PB; ++g) {
        // prefetch next row before the reduction barriers
        uint4 nxt[4];
        const uint4* pn = p + ROW_U4;
        if (g + 1 < PB) {
            #pragma unroll
            for (int j = 0; j < 4; ++j) nxt[j] = pn[j * 512 + t];
        }

        float d[4];
        #pragma unroll
        for (int j = 0; j < 4; ++j) {
            float4 lo, hi;
            unpack8(cur[j], lo, hi);
            d[j] = dot4(lo, v[2*j]) + dot4(hi, v[2*j+1]);
        }
        #pragma unroll
        for (int j = 0; j < 4; ++j) d[j] += __shfl_xor(d[j], 1);

        float e[4];
        #pragma unroll
        for (int j = 0; j < 4; ++j) e[j] = __expf(d[j]);

        float es = (e[0] + e[1]) + (e[2] + e[3]);   // each o counted 2x
        #pragma unroll
        for (int off = 32; off; off >>= 1) es += __shfl_xor(es, off);
        if (lane == 0) red8[wave] = es;
        __syncthreads();
        if (wave == 0) {
            float s = (lane < 8) ? red8[lane] : 0.f;
            s += __shfl_xor(s, 4); s += __shfl_xor(s, 2); s += __shfl_xor(s, 1);
            if (lane == 0) redS = s;
        }
        __syncthreads();
        const float inv = 2.0f / redS;

        #pragma unroll
        for (int j = 0; j < 4; ++j) {
            float4 lo, hi;
            unpack8(cur[j], lo, hi);
            const float c = e[j] * inv;
            fma4(acc[2*j],   c, lo);
            fma4(acc[2*j+1], c, hi);
        }

        #pragma unroll
        for (int j = 0; j < 4; ++j) cur[j] = nxt[j];
        p = pn;
    }

    float4* sp = reinterpret_cast<float4*>(part) + (size_t)blockIdx.x * ROW_C4;
    #pragma unroll
    for (int j = 0; j < 4; ++j) {
        const int u = j * 512 + t;
        sp[2*u]     = acc[2*j];
        sp[2*u + 1] = acc[2*j+1];
    }
}

// ---------------------------------------------------------------------------
// Reduce partials -> s, squash -> v, out, cumulative V. 256 x 256; 4 threads
// per output element; quad shfl combine; 16-lane butterfly for sum-of-squares.
// ---------------------------------------------------------------------------
__global__ __launch_bounds__(256) void k_reduce(const float* __restrict__ part,
                                                float* __restrict__ V,
                                                float* __restrict__ out,
                                                int G, int first) {
    const int t    = threadIdx.x;
    const int gidx = blockIdx.x * 64 + (t >> 2);   // o*16 + f
    const int q    = t & 3;
    const float* p = part + gidx;
    float a0 = 0.f, a1 = 0.f;
    int b = q;
    for (; b + 4 < G; b += 8) {
        a0 += p[(size_t)(b    ) * ROW_ELEMS];
        a1 += p[(size_t)(b + 4) * ROW_ELEMS];
    }
    for (; b < G; b += 4) a0 += p[(size_t)b * ROW_ELEMS];
    float s = a0 + a1;
    s += __shfl_xor(s, 1);
    s += __shfl_xor(s, 2);

    float sq = s * s;
    sq += __shfl_xor(sq, 4);
    sq += __shfl_xor(sq, 8);
    sq += __shfl_xor(sq, 16);
    sq += __shfl_xor(sq, 32);

    const float scale = sq / ((1.0f + sq) * sqrtf(sq));
    const float v = s * scale;

    out[gidx] = v;
    V[gidx]   = first ? v : (V[gidx] + v);
}

// ===========================================================================
// f32 fallback (only if workspace is unexpectedly small): R6-style kernels.
// ===========================================================================
__global__ __launch_bounds__(1024) void fb_uniform(const float* __restrict__ uh,
                                                   float* __restrict__ part,
                                                   int per_block) {
    const int t  = threadIdx.x;
    const int c0 = ((t >> 6) << 8) + (t & 63);
    float4 acc[4];
    #pragma unroll
    for (int j = 0; j < 4; ++j) acc[j] = make_float4(0.f, 0.f, 0.f, 0.f);
    const float4* p = reinterpret_cast<const float4*>(uh)
                    + (size_t)blockIdx.x * per_block * ROW_C4 + c0;
    for (int g = 0; g < per_block; ++g) {
        #pragma unroll
        for (int j = 0; j < 4; ++j) add4(acc[j], p[j * 64]);
        p += ROW_C4;
    }
    const float c = 1.0f / OUT_NODES;
    float4* sp = reinterpret_cast<float4*>(part) + (size_t)blockIdx.x * ROW_C4 + c0;
    #pragma unroll
    for (int j = 0; j < 4; ++j) {
        acc[j].x *= c; acc[j].y *= c; acc[j].z *= c; acc[j].w *= c;
        sp[j * 64] = acc[j];
    }
}

__global__ __launch_bounds__(1024) void fb_soft(const float* __restrict__ uh,
                                                const float* __restrict__ V,
                                                float* __restrict__ part,
                                                int per_block) {
    const int t    = threadIdx.x;
    const int wave = t >> 6;
    const int lane = t & 63;
    const int c0   = (wave << 8) + lane;
    __shared__ float red16[16];
    __shared__ float redS;

    float4 v[4];
    const float4* vp = reinterpret_cast<const float4*>(V) + c0;
    #pragma unroll
    for (int j = 0; j < 4; ++j) v[j] = vp[j * 64];

    float4 acc[4];
    #pragma unroll
    for (int j = 0; j < 4; ++j) acc[j] = make_float4(0.f, 0.f, 0.f, 0.f);

    const float4* p = reinterpret_cast<const float4*>(uh)
                    + (size_t)blockIdx.x * per_block * ROW_C4 + c0;
    for (int g = 0; g < per_block; ++g) {
        float4 u[4];
        #pragma unroll
        for (int j = 0; j < 4; ++j) u[j] = p[j * 64];
        float d[4];
        #pragma unroll
        for (int j = 0; j < 4; ++j) d[j] = dot4(u[j], v[j]);
        #pragma unroll
        for (int j = 0; j < 4; ++j) {
            d[j] += __shfl_xor(d[j], 1);
            d[j] += __shfl_xor(d[j], 2);
        }
        float e[4];
        float etot = 0.f;
        #pragma unroll
        for (int j = 0; j < 4; ++j) { e[j] = __expf(d[j]); etot += e[j]; }
        #pragma unroll
        for (int off = 32; off; off >>= 1) etot += __shfl_xor(etot, off);
        if (lane == 0) red16[wave] = etot;
        __syncthreads();
        if (wave == 0) {
            float s = (lane < 16) ? red16[lane] : 0.f;
            #pragma unroll
            for (int off = 8; off; off >>= 1) s += __shfl_xor(s, off);
            if (lane == 0) redS = s;
        }
        __syncthreads();
        const float inv = 4.0f / redS;
        #pragma unroll
        for (int j = 0; j < 4; ++j) fma4(acc[j], e[j] * inv, u[j]);
        p += ROW_C4;
    }
    float4* sp = reinterpret_cast<float4*>(part) + (size_t)blockIdx.x * ROW_C4 + c0;
    #pragma unroll
    for (int j = 0; j < 4; ++j) sp[j * 64] = acc[j];
}

// ---------------------------------------------------------------------------
extern "C" void kernel_launch(void* const* d_in, const int* in_sizes, int n_in,
                              void* d_out, int out_size, void* d_ws, size_t ws_size,
                              hipStream_t stream) {
    const float* uh  = (const float*)d_in[0];
    float*       out = (float*)d_out;

    char*  ws   = (char*)d_ws;
    float* V    = (float*)ws;                              // 64 KB
    float* part = (float*)(ws + 65536);                    // 512*64KB = 32 MB
    u16*   uh2  = (u16*)(ws + 65536 + (size_t)G_SOFT * ROW_ELEMS * 4);  // 128 MB

    const size_t need = 65536ull + (size_t)G_SOFT * ROW_ELEMS * 4ull
                      + (size_t)IN_NODES * ROW_ELEMS * 2ull;   // ~160 MB

    if (ws_size >= need) {
        k_uniform<<<G_UNI, 1024, 0, stream>>>(uh, uh2, part);
        k_reduce<<<256, 256, 0, stream>>>(part, V, out, G_UNI, 1);
        for (int it = 1; it < 3; ++it) {
            k_soft<<<G_SOFT, 512, 0, stream>>>(uh2, V, part);
            k_reduce<<<256, 256, 0, stream>>>(part, V, out, G_SOFT, 0);
        }
    } else {
        int G2 = 256;
        while (G2 > 4 && ws_size < 65536ull * (size_t)(G2 + 1)) G2 >>= 1;
        const int per_block = IN_NODES / G2;
        fb_uniform<<<G2, 1024, 0, stream>>>(uh, part, per_block);
        k_reduce<<<256, 256, 0, stream>>>(part, V, out, G2, 1);
        for (int it = 1; it < 3; ++it) {
            fb_soft<<<G2, 1024, 0, stream>>>(uh, V, part, per_block);
            k_reduce<<<256, 256, 0, stream>>>(part, V, out, G2, 0);
        }
    }
}